// Round 6
// baseline (28.654 us; speedup 1.0000x reference)
//
#include <hip/hip_runtime.h>
#include <math.h>

#define NQ 300
#define NQP 301              // padded row length for psmT
#define NT 30
#define NC 10
#define NTH 512
#define NWAVE 8
#define INFF 3.0e38f

__device__ __forceinline__ float sigf(float x){ return 1.0f/(1.0f + expf(-x)); }
__device__ __forceinline__ float softplusf(float x){ return fmaxf(x,0.0f) + log1pf(expf(-fabsf(x))); }
__device__ __forceinline__ float readlane_f(float v, int l){
  return __int_as_float(__builtin_amdgcn_readlane(__float_as_int(v), l));
}
__device__ __forceinline__ int readlane_i(int v, int l){
  return __builtin_amdgcn_readlane(v, l);
}

// ---- DPP wave64 reductions (result uniform via readlane 63) ----
template<int CTRL,int RMASK>
__device__ __forceinline__ float dppmin_f(float x){
  int t = __builtin_amdgcn_update_dpp(0x7f800000, __float_as_int(x), CTRL, RMASK, 0xf, false);
  return fminf(x, __int_as_float(t));
}
template<int CTRL,int RMASK>
__device__ __forceinline__ unsigned dppmin_u(unsigned x){
  unsigned t = (unsigned)__builtin_amdgcn_update_dpp((int)0xFFFFFFFFu, (int)x, CTRL, RMASK, 0xf, false);
  return x < t ? x : t;
}
template<int CTRL,int RMASK>
__device__ __forceinline__ float dppadd_f(float x){
  int t = __builtin_amdgcn_update_dpp(0, __float_as_int(x), CTRL, RMASK, 0xf, false);
  return x + __int_as_float(t);
}
// argmin with smallest-index tie-break (matches np.argmin first-occurrence)
__device__ __forceinline__ void wave_argmin64(float v, unsigned idx, float &ov, int &oj){
  float x = v;
  x = dppmin_f<0x111,0xf>(x); x = dppmin_f<0x112,0xf>(x);
  x = dppmin_f<0x114,0xf>(x); x = dppmin_f<0x118,0xf>(x);
  x = dppmin_f<0x142,0xa>(x); x = dppmin_f<0x143,0xc>(x);
  float vmin = __int_as_float(__builtin_amdgcn_readlane(__float_as_int(x), 63));
  unsigned c = (v == vmin) ? idx : 0xFFFFFFFFu;
  c = dppmin_u<0x111,0xf>(c); c = dppmin_u<0x112,0xf>(c);
  c = dppmin_u<0x114,0xf>(c); c = dppmin_u<0x118,0xf>(c);
  c = dppmin_u<0x142,0xa>(c); c = dppmin_u<0x143,0xc>(c);
  oj = __builtin_amdgcn_readlane((int)c, 63);
  ov = vmin;
}
__device__ __forceinline__ float wave_sum64(float v){
  float x = v;
  x = dppadd_f<0x111,0xf>(x); x = dppadd_f<0x112,0xf>(x);
  x = dppadd_f<0x114,0xf>(x); x = dppadd_f<0x118,0xf>(x);
  x = dppadd_f<0x142,0xa>(x); x = dppadd_f<0x143,0xc>(x);
  return __int_as_float(__builtin_amdgcn_readlane(__float_as_int(x), 63));
}

// One block per batch element, 8 waves. Lane ln owns columns ln+64k (k=0..4)
// with the q-box data in registers; waves co-fill the 30x300 cost matrix in
// LDS (row minima via DPP); wave 0 does greedy claim (LDS atomicMin) + SAP
// for contested rows with u, v, minv, pcol, way ALL in registers (pcol[j1]
// via uniform-switch + readlane); loss computed from register q data.
__global__ __launch_bounds__(NTH) void hm_main(
    const float* __restrict__ logits,   // [64,300,10]
    const float* __restrict__ pbox,     // [64,300,4] cxcywh
    const int*   __restrict__ labels,   // [64,30]
    const float* __restrict__ tbox,     // [64,30,4] cxcywh
    float* __restrict__ out)            // [1]
{
  const int b = blockIdx.x;
  const int tid = threadIdx.x;
  const int wv = tid >> 6, ln = tid & 63;

  __shared__ float D[NT*NQ];
  __shared__ float psmT[NC*NQP];        // sigmoid table, transposed [c][q]
  __shared__ float traw[NT][4], txy[NT][4], tarea[NT];
  __shared__ int   tlab[NT];
  __shared__ float uu[NT+1];            // row minima handoff to wave 0
  __shared__ int   pcol[NQ];            // 0 = free, else assigned row 1..30
  __shared__ int   claimA[NQ];          // greedy claim array
  __shared__ int   rargm[NT];           // row argmin column
  __shared__ float redw[NWAVE];

  const bool v4 = ln < (NQ - 256);      // slot 4 valid for ln<44

  // per-lane q-box registers (5 slots, col = ln + 64k), coalesced float4 loads
  float qcx[5],qcy[5],qw[5],qh[5],qx0[5],qy0[5],qx1[5],qy1[5],qar[5];
  {
    const float4* pb4 = (const float4*)pbox + (size_t)b*NQ;
    #pragma unroll
    for (int k = 0; k < 5; ++k) {
      float4 s = (k < 4 || v4) ? pb4[ln + (k<<6)] : make_float4(0.f,0.f,0.f,0.f);
      qcx[k]=s.x; qcy[k]=s.y; qw[k]=s.z; qh[k]=s.w;
      qx0[k]=s.x-0.5f*s.z; qy0[k]=s.y-0.5f*s.w;
      qx1[k]=s.x+0.5f*s.z; qy1[k]=s.y+0.5f*s.w;
      qar[k]=(qx1[k]-qx0[k])*(qy1[k]-qy0[k]);
    }
  }
  if (tid < NT) {
    float4 s = ((const float4*)tbox)[(size_t)b*NT + tid];
    traw[tid][0]=s.x; traw[tid][1]=s.y; traw[tid][2]=s.z; traw[tid][3]=s.w;
    float x0=s.x-0.5f*s.z, y0=s.y-0.5f*s.w, x1=s.x+0.5f*s.z, y1=s.y+0.5f*s.w;
    txy[tid][0]=x0; txy[tid][1]=y0; txy[tid][2]=x1; txy[tid][3]=y1;
    tarea[tid]=(x1-x0)*(y1-y0);
    tlab[tid]=labels[b*NT + tid];
  }
  for (int j = tid; j < NQ; j += NTH) { pcol[j]=0; claimA[j]=0x7fffffff; }

  // sigmoid table (transposed) + focal t=0 baseline partial sum
  float tot = 0.f;
  for (int e = tid; e < NQ*NC; e += NTH) {
    float x = logits[(size_t)b*NQ*NC + e];
    float pr = sigf(x);
    int q = e / NC, c = e - q*NC;
    psmT[c*NQP + q] = pr;
    tot += 0.75f * softplusf(x) * pr * pr;
  }
  __syncthreads();

  // fused cost fill + row minima (wave wv: rows wv, wv+8, ...)
  for (int i = wv; i < NT; i += NWAVE) {
    const float t0=traw[i][0], t1=traw[i][1], t2=traw[i][2], t3=traw[i][3];
    const float x0=txy[i][0], y0=txy[i][1], x1=txy[i][2], y1=txy[i][3];
    const float ta=tarea[i];
    const float* prow = &psmT[tlab[i]*NQP];
    float bv=INFF; unsigned bj=0xFFFFFFFFu;
    #pragma unroll
    for (int k = 0; k < 5; ++k) {
      if (k < 4 || v4) {
        int q = ln + (k<<6);
        float cb = fabsf(qcx[k]-t0)+fabsf(qcy[k]-t1)+fabsf(qw[k]-t2)+fabsf(qh[k]-t3);
        float lt0=fmaxf(qx0[k],x0), lt1=fmaxf(qy0[k],y0);
        float rb0=fminf(qx1[k],x1), rb1=fminf(qy1[k],y1);
        float iw=fmaxf(rb0-lt0,0.f), ih=fmaxf(rb1-lt1,0.f);
        float inter=iw*ih;
        float uni=qar[k]+ta-inter;
        float iou=inter/uni;
        float c0=fminf(qx0[k],x0), c1=fminf(qy0[k],y0);
        float c2=fmaxf(qx1[k],x1), c3=fmaxf(qy1[k],y1);
        float cw=fmaxf(c2-c0,0.f), ch=fmaxf(c3-c1,0.f);
        float areac=cw*ch;
        float g=iou-(areac-uni)/areac;
        float dval = 5.f*cb - 2.f*prow[q] - 2.f*g;
        D[i*NQ+q] = dval;
        if (dval < bv) { bv=dval; bj=(unsigned)q; }   // ascending q: first-min kept
      }
    }
    float vmin; int jmin;
    wave_argmin64(bv, bj, vmin, jmin);
    if (ln == 0) { uu[i+1]=vmin; rargm[i]=jmin; }     // u[i] = row min (feasible dual)
  }
  __syncthreads();

  // ---- wave 0: greedy claim + register-state SAP for contested rows ----
  if (wv == 0) {
    const int lane = ln;
    float u_reg = (lane < NT) ? uu[lane+1] : 0.f;
    float vv0=0.f,vv1=0.f,vv2=0.f,vv3=0.f,vv4=0.f;
    // greedy: row claims its argmin col; min-row wins (== sequential first-wins)
    int jm = (lane < NT) ? rargm[lane] : 0;
    bool winner = false;
    if (lane < NT) {
      atomicMin(&claimA[jm], lane);
      winner = (claimA[jm] == lane);
      if (winner) pcol[jm] = lane + 1;
    }
    unsigned freerows = (unsigned)__ballot(lane < NT && !winner);
    // pull pcol into registers (5 slots/lane); way slots live in regs too
    int pc0=pcol[lane], pc1=pcol[lane+64], pc2=pcol[lane+128], pc3=pcol[lane+192];
    int pc4 = v4 ? pcol[lane+256] : 0;
    int wy0=0, wy1=0, wy2=0, wy3=0, wy4=0;

    while (freerows) {
      int fr = __builtin_ctz(freerows); freerows &= (freerows - 1);
      const int it = fr + 1;
      float mn0=INFF,mn1=INFF,mn2=INFF,mn3=INFF,mn4=INFF;
      int usedm = 0;
      bool onpath = (lane == fr);
      int j0 = -1, i0 = it, j1 = 0;
      for (;;) {
        float ui0 = readlane_f(u_reg, i0-1);
        const float* Drow = &D[(i0-1)*NQ];
        float lval = INFF; unsigned lidx = 0xFFFFFFFFu;
        #define SCAN_K(K, MN, VV, WY) \
          if ((K < 4 || v4) && !((usedm>>K)&1)) { \
            float cur = Drow[lane + (K<<6)] - ui0 - VV; \
            if (cur < MN) { MN = cur; WY = j0; } \
            if (MN < lval) { lval = MN; lidx = (unsigned)(lane + (K<<6)); } \
          }
        SCAN_K(0, mn0, vv0, wy0)
        SCAN_K(1, mn1, vv1, wy1)
        SCAN_K(2, mn2, vv2, wy2)
        SCAN_K(3, mn3, vv3, wy3)
        SCAN_K(4, mn4, vv4, wy4)
        #undef SCAN_K
        float delta; int j1i;
        wave_argmin64(lval, lidx, delta, j1i);
        j1 = j1i;
        if (onpath) u_reg += delta;
        #define UPD_K(K, MN, VV) if ((usedm>>K)&1) VV -= delta; else MN -= delta;
        UPD_K(0, mn0, vv0) UPD_K(1, mn1, vv1) UPD_K(2, mn2, vv2)
        UPD_K(3, mn3, vv3) UPD_K(4, mn4, vv4)
        #undef UPD_K
        // pcol[j1] via uniform slot select + readlane
        int slot = j1 >> 6, src = j1 & 63;
        int pv;
        switch (slot) { case 0: pv=pc0; break; case 1: pv=pc1; break;
                        case 2: pv=pc2; break; case 3: pv=pc3; break; default: pv=pc4; }
        int pj1 = readlane_i(pv, src);
        if (pj1 == 0) break;                 // free column reached
        onpath = onpath || (lane == (pj1-1));
        if (lane == src) usedm |= (1 << slot);
        j0 = j1; i0 = pj1;
      }
      // augment along register predecessors (uniform walk)
      int j = j1;
      for (;;) {
        int slot = j >> 6, src = j & 63;
        int wval;
        switch (slot) { case 0: wval=wy0; break; case 1: wval=wy1; break;
                        case 2: wval=wy2; break; case 3: wval=wy3; break; default: wval=wy4; }
        int jp = readlane_i(wval, src);
        int rr;
        if (jp < 0) rr = it;
        else {
          int s2 = jp >> 6, l2 = jp & 63;
          int pv2;
          switch (s2) { case 0: pv2=pc0; break; case 1: pv2=pc1; break;
                        case 2: pv2=pc2; break; case 3: pv2=pc3; break; default: pv2=pc4; }
          rr = readlane_i(pv2, l2);
        }
        switch (slot) {
          case 0: if (lane==src) pc0=rr; break;
          case 1: if (lane==src) pc1=rr; break;
          case 2: if (lane==src) pc2=rr; break;
          case 3: if (lane==src) pc3=rr; break;
          default: if (lane==src) pc4=rr; break;
        }
        if (jp < 0) break;
        j = jp;
      }
    }
    // publish final assignment for the loss phase
    pcol[lane]=pc0; pcol[lane+64]=pc1; pcol[lane+128]=pc2; pcol[lane+192]=pc3;
    if (v4) pcol[lane+256]=pc4;
  }
  __syncthreads();

  // matched-pair losses: wave wv<5 handles column q = ln + 64*wv (slot wv regs)
  if (wv < 5 && (wv < 4 || v4)) {
    int q = ln + (wv<<6);
    int row = pcol[q];
    if (row > 0) {
      int ti = row-1;
      float scx,scy,sw,sh,sx0,sy0,sx1,sy1,sar;
      switch (wv) {
        case 0: scx=qcx[0];scy=qcy[0];sw=qw[0];sh=qh[0];sx0=qx0[0];sy0=qy0[0];sx1=qx1[0];sy1=qy1[0];sar=qar[0]; break;
        case 1: scx=qcx[1];scy=qcy[1];sw=qw[1];sh=qh[1];sx0=qx0[1];sy0=qy0[1];sx1=qx1[1];sy1=qy1[1];sar=qar[1]; break;
        case 2: scx=qcx[2];scy=qcy[2];sw=qw[2];sh=qh[2];sx0=qx0[2];sy0=qy0[2];sx1=qx1[2];sy1=qy1[2];sar=qar[2]; break;
        case 3: scx=qcx[3];scy=qcy[3];sw=qw[3];sh=qh[3];sx0=qx0[3];sy0=qy0[3];sx1=qx1[3];sy1=qy1[3];sar=qar[3]; break;
        default: scx=qcx[4];scy=qcy[4];sw=qw[4];sh=qh[4];sx0=qx0[4];sy0=qy0[4];sx1=qx1[4];sy1=qy1[4];sar=qar[4]; break;
      }
      float l1 = fabsf(scx-traw[ti][0])+fabsf(scy-traw[ti][1])
               + fabsf(sw -traw[ti][2])+fabsf(sh -traw[ti][3]);
      float lt0=fmaxf(sx0,txy[ti][0]), lt1=fmaxf(sy0,txy[ti][1]);
      float rb0=fminf(sx1,txy[ti][2]), rb1=fminf(sy1,txy[ti][3]);
      float iw=fmaxf(rb0-lt0,0.f), ih=fmaxf(rb1-lt1,0.f);
      float inter=iw*ih;
      float uni=sar+tarea[ti]-inter;
      float iou=inter/uni;
      float c0=fminf(sx0,txy[ti][0]), c1=fminf(sy0,txy[ti][1]);
      float c2=fmaxf(sx1,txy[ti][2]), c3=fmaxf(sy1,txy[ti][3]);
      float cw=fmaxf(c2-c0,0.f), ch=fmaxf(c3-c1,0.f);
      float areac=cw*ch;
      float g=iou-(areac-uni)/areac;
      // focal: replace t=0 term with t=1 term at the matched class
      float x  = logits[((size_t)b*NQ+q)*NC + tlab[ti]];
      float pr = psmT[tlab[ti]*NQP + q];
      float sp = softplusf(x);
      tot += (0.25f*(sp - x)*(1.f-pr)*(1.f-pr) - 0.75f*sp*pr*pr) + 5.f*l1 + 2.f*(1.f-g);
    }
  }
  // block reduction: DPP wave sum -> LDS -> single atomicAdd per block
  float wsum = wave_sum64(tot);
  if (ln == 0) redw[wv] = wsum;
  __syncthreads();
  if (tid == 0) {
    float s = 0.f;
    #pragma unroll
    for (int w = 0; w < NWAVE; ++w) s += redw[w];
    atomicAdd(out, s * (1.0f/1920.0f));
  }
}

extern "C" void kernel_launch(void* const* d_in, const int* in_sizes, int n_in,
                              void* d_out, int out_size, void* d_ws, size_t ws_size,
                              hipStream_t stream) {
  const float* logits = (const float*)d_in[0];
  const float* pbox   = (const float*)d_in[1];
  const int*   labels = (const int*)d_in[2];
  const float* tbox   = (const float*)d_in[3];
  hipMemsetAsync(d_out, 0, sizeof(float), stream);   // out accumulated via atomicAdd
  hm_main<<<dim3(64), dim3(NTH), 0, stream>>>(logits, pbox, labels, tbox, (float*)d_out);
}

// Round 7
// 24.825 us; speedup vs baseline: 1.1542x; 1.1542x over previous
//
#include <hip/hip_runtime.h>
#include <math.h>

#define NQ 300
#define NQP 301              // padded row length for psmT
#define NT 30
#define NC 10
#define NTH 512
#define NWAVE 8
#define INFF 3.0e38f

// fast transcendentals: v_exp/v_log based; ~1e-5 rel error, far below the
// matching margin (O(0.1)) and loss threshold (0.5625, bf16-granular).
__device__ __forceinline__ float sigf(float x){ return 1.0f/(1.0f + __expf(-x)); }
__device__ __forceinline__ float softplusf(float x){ return fmaxf(x,0.0f) + __logf(1.0f + __expf(-fabsf(x))); }
__device__ __forceinline__ float focal0(float x){   // 0.75*softplus(x)*sigmoid(x)^2
  float pr = sigf(x);
  return 0.75f * softplusf(x) * pr * pr;
}
__device__ __forceinline__ float readlane_f(float v, int l){
  return __int_as_float(__builtin_amdgcn_readlane(__float_as_int(v), l));
}
__device__ __forceinline__ int readlane_i(int v, int l){
  return __builtin_amdgcn_readlane(v, l);
}

// ---- DPP wave64 reductions (result uniform via readlane 63) ----
template<int CTRL,int RMASK>
__device__ __forceinline__ float dppmin_f(float x){
  int t = __builtin_amdgcn_update_dpp(0x7f800000, __float_as_int(x), CTRL, RMASK, 0xf, false);
  return fminf(x, __int_as_float(t));
}
template<int CTRL,int RMASK>
__device__ __forceinline__ unsigned dppmin_u(unsigned x){
  unsigned t = (unsigned)__builtin_amdgcn_update_dpp((int)0xFFFFFFFFu, (int)x, CTRL, RMASK, 0xf, false);
  return x < t ? x : t;
}
template<int CTRL,int RMASK>
__device__ __forceinline__ float dppadd_f(float x){
  int t = __builtin_amdgcn_update_dpp(0, __float_as_int(x), CTRL, RMASK, 0xf, false);
  return x + __int_as_float(t);
}
// argmin with smallest-index tie-break (matches np.argmin first-occurrence)
__device__ __forceinline__ void wave_argmin64(float v, unsigned idx, float &ov, int &oj){
  float x = v;
  x = dppmin_f<0x111,0xf>(x); x = dppmin_f<0x112,0xf>(x);
  x = dppmin_f<0x114,0xf>(x); x = dppmin_f<0x118,0xf>(x);
  x = dppmin_f<0x142,0xa>(x); x = dppmin_f<0x143,0xc>(x);
  float vmin = __int_as_float(__builtin_amdgcn_readlane(__float_as_int(x), 63));
  unsigned c = (v == vmin) ? idx : 0xFFFFFFFFu;
  c = dppmin_u<0x111,0xf>(c); c = dppmin_u<0x112,0xf>(c);
  c = dppmin_u<0x114,0xf>(c); c = dppmin_u<0x118,0xf>(c);
  c = dppmin_u<0x142,0xa>(c); c = dppmin_u<0x143,0xc>(c);
  oj = __builtin_amdgcn_readlane((int)c, 63);
  ov = vmin;
}
__device__ __forceinline__ float wave_sum64(float v){
  float x = v;
  x = dppadd_f<0x111,0xf>(x); x = dppadd_f<0x112,0xf>(x);
  x = dppadd_f<0x114,0xf>(x); x = dppadd_f<0x118,0xf>(x);
  x = dppadd_f<0x142,0xa>(x); x = dppadd_f<0x143,0xc>(x);
  return __int_as_float(__builtin_amdgcn_readlane(__float_as_int(x), 63));
}

// Grid 128. Blocks 0..63: per-batch matching + matched-pair loss terms.
// Blocks 64..127: the focal t=0 baseline sum over batch (bid-64)'s logits --
// independent of the matching, so it runs concurrently on idle CUs instead
// of sitting on the matching critical path.
__global__ __launch_bounds__(NTH) void hm_main(
    const float* __restrict__ logits,   // [64,300,10]
    const float* __restrict__ pbox,     // [64,300,4] cxcywh
    const int*   __restrict__ labels,   // [64,30]
    const float* __restrict__ tbox,     // [64,30,4] cxcywh
    float* __restrict__ out)            // [1]
{
  const int bid = blockIdx.x;
  const int tid = threadIdx.x;
  const int wv = tid >> 6, ln = tid & 63;

  __shared__ float D[NT*NQ];
  __shared__ float psmT[NC*NQP];        // sigmoid table, transposed [c][q]
  __shared__ float traw[NT][4], txy[NT][4], tarea[NT];
  __shared__ int   tlab[NT];
  __shared__ float uu[NT+1];            // row minima handoff to wave 0
  __shared__ int   pcol[NQ];            // 0 = free, else assigned row 1..30
  __shared__ int   claimA[NQ];          // greedy claim array
  __shared__ int   rargm[NT];           // row argmin column
  __shared__ float redw[NWAVE];

  // ---------------- auxiliary blocks: focal t=0 baseline ----------------
  if (bid >= 64) {
    const int b = bid - 64;
    const float4* lg4 = (const float4*)(logits + (size_t)b*NQ*NC); // 750 float4
    float tot = 0.f;
    for (int e = tid; e < NQ*NC/4; e += NTH) {
      float4 v = lg4[e];
      tot += focal0(v.x) + focal0(v.y) + focal0(v.z) + focal0(v.w);
    }
    float wsum = wave_sum64(tot);
    if (ln == 0) redw[wv] = wsum;
    __syncthreads();
    if (tid == 0) {
      float s = 0.f;
      #pragma unroll
      for (int w = 0; w < NWAVE; ++w) s += redw[w];
      atomicAdd(out, s * (1.0f/1920.0f));
    }
    return;
  }

  // ---------------- main blocks: matching + matched-pair loss ----------------
  const int b = bid;
  const bool v4 = ln < (NQ - 256);      // slot 4 valid for ln<44

  // per-lane q-box registers (5 slots, col = ln + 64k), coalesced float4 loads
  float qcx[5],qcy[5],qw[5],qh[5],qx0[5],qy0[5],qx1[5],qy1[5],qar[5];
  {
    const float4* pb4 = (const float4*)pbox + (size_t)b*NQ;
    #pragma unroll
    for (int k = 0; k < 5; ++k) {
      float4 s = (k < 4 || v4) ? pb4[ln + (k<<6)] : make_float4(0.f,0.f,0.f,0.f);
      qcx[k]=s.x; qcy[k]=s.y; qw[k]=s.z; qh[k]=s.w;
      qx0[k]=s.x-0.5f*s.z; qy0[k]=s.y-0.5f*s.w;
      qx1[k]=s.x+0.5f*s.z; qy1[k]=s.y+0.5f*s.w;
      qar[k]=(qx1[k]-qx0[k])*(qy1[k]-qy0[k]);
    }
  }
  if (tid < NT) {
    float4 s = ((const float4*)tbox)[(size_t)b*NT + tid];
    traw[tid][0]=s.x; traw[tid][1]=s.y; traw[tid][2]=s.z; traw[tid][3]=s.w;
    float x0=s.x-0.5f*s.z, y0=s.y-0.5f*s.w, x1=s.x+0.5f*s.z, y1=s.y+0.5f*s.w;
    txy[tid][0]=x0; txy[tid][1]=y0; txy[tid][2]=x1; txy[tid][3]=y1;
    tarea[tid]=(x1-x0)*(y1-y0);
    tlab[tid]=labels[b*NT + tid];
  }
  for (int j = tid; j < NQ; j += NTH) { pcol[j]=0; claimA[j]=0x7fffffff; }

  // sigmoid table only (baseline sum moved to aux blocks), float4 loads
  {
    const float4* lg4 = (const float4*)(logits + (size_t)b*NQ*NC);
    for (int e4 = tid; e4 < NQ*NC/4; e4 += NTH) {
      float4 v = lg4[e4];
      int e = e4 << 2;
      #pragma unroll
      for (int j = 0; j < 4; ++j) {
        float x = (j==0)?v.x:(j==1)?v.y:(j==2)?v.z:v.w;
        int ee = e + j, q = ee / NC, c = ee - q*NC;
        psmT[c*NQP + q] = sigf(x);
      }
    }
  }
  __syncthreads();

  // fused cost fill + row minima (wave wv: rows wv, wv+8, ...)
  for (int i = wv; i < NT; i += NWAVE) {
    const float t0=traw[i][0], t1=traw[i][1], t2=traw[i][2], t3=traw[i][3];
    const float x0=txy[i][0], y0=txy[i][1], x1=txy[i][2], y1=txy[i][3];
    const float ta=tarea[i];
    const float* prow = &psmT[tlab[i]*NQP];
    float bv=INFF; unsigned bj=0xFFFFFFFFu;
    #pragma unroll
    for (int k = 0; k < 5; ++k) {
      if (k < 4 || v4) {
        int q = ln + (k<<6);
        float cb = fabsf(qcx[k]-t0)+fabsf(qcy[k]-t1)+fabsf(qw[k]-t2)+fabsf(qh[k]-t3);
        float lt0=fmaxf(qx0[k],x0), lt1=fmaxf(qy0[k],y0);
        float rb0=fminf(qx1[k],x1), rb1=fminf(qy1[k],y1);
        float iw=fmaxf(rb0-lt0,0.f), ih=fmaxf(rb1-lt1,0.f);
        float inter=iw*ih;
        float uni=qar[k]+ta-inter;
        float iou=inter/uni;
        float c0=fminf(qx0[k],x0), c1=fminf(qy0[k],y0);
        float c2=fmaxf(qx1[k],x1), c3=fmaxf(qy1[k],y1);
        float cw=fmaxf(c2-c0,0.f), ch=fmaxf(c3-c1,0.f);
        float areac=cw*ch;
        float g=iou-(areac-uni)/areac;
        float dval = 5.f*cb - 2.f*prow[q] - 2.f*g;
        D[i*NQ+q] = dval;
        if (dval < bv) { bv=dval; bj=(unsigned)q; }   // ascending q: first-min kept
      }
    }
    float vmin; int jmin;
    wave_argmin64(bv, bj, vmin, jmin);
    if (ln == 0) { uu[i+1]=vmin; rargm[i]=jmin; }     // u[i] = row min (feasible dual)
  }
  __syncthreads();

  // ---- wave 0: greedy claim + register-state SAP for contested rows ----
  if (wv == 0) {
    const int lane = ln;
    float u_reg = (lane < NT) ? uu[lane+1] : 0.f;
    float vv0=0.f,vv1=0.f,vv2=0.f,vv3=0.f,vv4=0.f;
    // greedy: row claims its argmin col; min-row wins (== sequential first-wins)
    int jm = (lane < NT) ? rargm[lane] : 0;
    bool winner = false;
    if (lane < NT) {
      atomicMin(&claimA[jm], lane);
      winner = (claimA[jm] == lane);
      if (winner) pcol[jm] = lane + 1;
    }
    unsigned freerows = (unsigned)__ballot(lane < NT && !winner);
    // pull pcol into registers (5 slots/lane); way slots live in regs too
    int pc0=pcol[lane], pc1=pcol[lane+64], pc2=pcol[lane+128], pc3=pcol[lane+192];
    int pc4 = v4 ? pcol[lane+256] : 0;
    int wy0=0, wy1=0, wy2=0, wy3=0, wy4=0;

    while (freerows) {
      int fr = __builtin_ctz(freerows); freerows &= (freerows - 1);
      const int it = fr + 1;
      float mn0=INFF,mn1=INFF,mn2=INFF,mn3=INFF,mn4=INFF;
      int usedm = 0;
      bool onpath = (lane == fr);
      int j0 = -1, i0 = it, j1 = 0;
      for (;;) {
        float ui0 = readlane_f(u_reg, i0-1);
        const float* Drow = &D[(i0-1)*NQ];
        float lval = INFF; unsigned lidx = 0xFFFFFFFFu;
        #define SCAN_K(K, MN, VV, WY) \
          if ((K < 4 || v4) && !((usedm>>K)&1)) { \
            float cur = Drow[lane + (K<<6)] - ui0 - VV; \
            if (cur < MN) { MN = cur; WY = j0; } \
            if (MN < lval) { lval = MN; lidx = (unsigned)(lane + (K<<6)); } \
          }
        SCAN_K(0, mn0, vv0, wy0)
        SCAN_K(1, mn1, vv1, wy1)
        SCAN_K(2, mn2, vv2, wy2)
        SCAN_K(3, mn3, vv3, wy3)
        SCAN_K(4, mn4, vv4, wy4)
        #undef SCAN_K
        float delta; int j1i;
        wave_argmin64(lval, lidx, delta, j1i);
        j1 = j1i;
        if (onpath) u_reg += delta;
        #define UPD_K(K, MN, VV) if ((usedm>>K)&1) VV -= delta; else MN -= delta;
        UPD_K(0, mn0, vv0) UPD_K(1, mn1, vv1) UPD_K(2, mn2, vv2)
        UPD_K(3, mn3, vv3) UPD_K(4, mn4, vv4)
        #undef UPD_K
        // pcol[j1] via uniform slot select + readlane
        int slot = j1 >> 6, src = j1 & 63;
        int pv;
        switch (slot) { case 0: pv=pc0; break; case 1: pv=pc1; break;
                        case 2: pv=pc2; break; case 3: pv=pc3; break; default: pv=pc4; }
        int pj1 = readlane_i(pv, src);
        if (pj1 == 0) break;                 // free column reached
        onpath = onpath || (lane == (pj1-1));
        if (lane == src) usedm |= (1 << slot);
        j0 = j1; i0 = pj1;
      }
      // augment along register predecessors (uniform walk)
      int j = j1;
      for (;;) {
        int slot = j >> 6, src = j & 63;
        int wval;
        switch (slot) { case 0: wval=wy0; break; case 1: wval=wy1; break;
                        case 2: wval=wy2; break; case 3: wval=wy3; break; default: wval=wy4; }
        int jp = readlane_i(wval, src);
        int rr;
        if (jp < 0) rr = it;
        else {
          int s2 = jp >> 6, l2 = jp & 63;
          int pv2;
          switch (s2) { case 0: pv2=pc0; break; case 1: pv2=pc1; break;
                        case 2: pv2=pc2; break; case 3: pv2=pc3; break; default: pv2=pc4; }
          rr = readlane_i(pv2, l2);
        }
        switch (slot) {
          case 0: if (lane==src) pc0=rr; break;
          case 1: if (lane==src) pc1=rr; break;
          case 2: if (lane==src) pc2=rr; break;
          case 3: if (lane==src) pc3=rr; break;
          default: if (lane==src) pc4=rr; break;
        }
        if (jp < 0) break;
        j = jp;
      }
    }
    // publish final assignment for the loss phase
    pcol[lane]=pc0; pcol[lane+64]=pc1; pcol[lane+128]=pc2; pcol[lane+192]=pc3;
    if (v4) pcol[lane+256]=pc4;
  }
  __syncthreads();

  // matched-pair losses: wave wv<5 handles column q = ln + 64*wv (slot wv regs)
  float tot = 0.f;
  if (wv < 5 && (wv < 4 || v4)) {
    int q = ln + (wv<<6);
    int row = pcol[q];
    if (row > 0) {
      int ti = row-1;
      float scx,scy,sw,sh,sx0,sy0,sx1,sy1,sar;
      switch (wv) {
        case 0: scx=qcx[0];scy=qcy[0];sw=qw[0];sh=qh[0];sx0=qx0[0];sy0=qy0[0];sx1=qx1[0];sy1=qy1[0];sar=qar[0]; break;
        case 1: scx=qcx[1];scy=qcy[1];sw=qw[1];sh=qh[1];sx0=qx0[1];sy0=qy0[1];sx1=qx1[1];sy1=qy1[1];sar=qar[1]; break;
        case 2: scx=qcx[2];scy=qcy[2];sw=qw[2];sh=qh[2];sx0=qx0[2];sy0=qy0[2];sx1=qx1[2];sy1=qy1[2];sar=qar[2]; break;
        case 3: scx=qcx[3];scy=qcy[3];sw=qw[3];sh=qh[3];sx0=qx0[3];sy0=qy0[3];sx1=qx1[3];sy1=qy1[3];sar=qar[3]; break;
        default: scx=qcx[4];scy=qcy[4];sw=qw[4];sh=qh[4];sx0=qx0[4];sy0=qy0[4];sx1=qx1[4];sy1=qy1[4];sar=qar[4]; break;
      }
      float l1 = fabsf(scx-traw[ti][0])+fabsf(scy-traw[ti][1])
               + fabsf(sw -traw[ti][2])+fabsf(sh -traw[ti][3]);
      float lt0=fmaxf(sx0,txy[ti][0]), lt1=fmaxf(sy0,txy[ti][1]);
      float rb0=fminf(sx1,txy[ti][2]), rb1=fminf(sy1,txy[ti][3]);
      float iw=fmaxf(rb0-lt0,0.f), ih=fmaxf(rb1-lt1,0.f);
      float inter=iw*ih;
      float uni=sar+tarea[ti]-inter;
      float iou=inter/uni;
      float c0=fminf(sx0,txy[ti][0]), c1=fminf(sy0,txy[ti][1]);
      float c2=fmaxf(sx1,txy[ti][2]), c3=fmaxf(sy1,txy[ti][3]);
      float cw=fmaxf(c2-c0,0.f), ch=fmaxf(c3-c1,0.f);
      float areac=cw*ch;
      float g=iou-(areac-uni)/areac;
      // focal: replace t=0 term with t=1 term at the matched class
      float x  = logits[((size_t)b*NQ+q)*NC + tlab[ti]];
      float pr = psmT[tlab[ti]*NQP + q];
      float sp = softplusf(x);
      tot += (0.25f*(sp - x)*(1.f-pr)*(1.f-pr) - 0.75f*sp*pr*pr) + 5.f*l1 + 2.f*(1.f-g);
    }
  }
  // block reduction: DPP wave sum -> LDS -> single atomicAdd per block
  float wsum = wave_sum64(tot);
  if (ln == 0) redw[wv] = wsum;
  __syncthreads();
  if (tid == 0) {
    float s = 0.f;
    #pragma unroll
    for (int w = 0; w < NWAVE; ++w) s += redw[w];
    atomicAdd(out, s * (1.0f/1920.0f));
  }
}

extern "C" void kernel_launch(void* const* d_in, const int* in_sizes, int n_in,
                              void* d_out, int out_size, void* d_ws, size_t ws_size,
                              hipStream_t stream) {
  const float* logits = (const float*)d_in[0];
  const float* pbox   = (const float*)d_in[1];
  const int*   labels = (const int*)d_in[2];
  const float* tbox   = (const float*)d_in[3];
  hipMemsetAsync(d_out, 0, sizeof(float), stream);   // out accumulated via atomicAdd
  hm_main<<<dim3(128), dim3(NTH), 0, stream>>>(logits, pbox, labels, tbox, (float*)d_out);
}